// Round 3
// baseline (4018.646 us; speedup 1.0000x reference)
//
#include <hip/hip_runtime.h>
#include <stdint.h>

#define T_ 1024
#define E_ 1024
#define L_ 8
#define H_ 16
#define ROWS_ 4096   // B*T

typedef __attribute__((ext_vector_type(8))) short bh8;   // 8 x bf16 (MFMA A/B frag)
typedef __attribute__((ext_vector_type(4))) short sv4;
typedef __attribute__((ext_vector_type(4))) float fv4;
typedef __attribute__((ext_vector_type(4))) unsigned int uv4;
typedef __attribute__((ext_vector_type(2))) unsigned int uv2;

#define MFMA(a, b, c) __builtin_amdgcn_mfma_f32_16x16x32_bf16(a, b, c, 0, 0, 0)

__device__ __forceinline__ short f2bf(float f) {
  union { float f; unsigned u; } a; a.f = f;
  unsigned r = a.u + 0x7FFFu + ((a.u >> 16) & 1u);   // RNE
  return (short)(r >> 16);
}

// global -> LDS direct copy, 16B per lane. LDS dest must be wave-uniform base.
__device__ __forceinline__ void gload16(const void* g, void* l) {
  auto gp = reinterpret_cast<__attribute__((address_space(1))) char*>(
      reinterpret_cast<uintptr_t>(g));
  auto lp = reinterpret_cast<__attribute__((address_space(3))) char*>(
      reinterpret_cast<uintptr_t>(l));
  __builtin_amdgcn_global_load_lds(gp, lp, 16, 0, 0);
}

// ---------------- embedding: x[row] = wte[tok[row]] + wpe[row%T] ----------------
__global__ __launch_bounds__(256) void k_embed(const int* __restrict__ tok,
                                               const float* __restrict__ wte,
                                               const float* __restrict__ wpe,
                                               float* __restrict__ x) {
  int row = blockIdx.x;
  int t = row & (T_ - 1);
  int tk = tok[row];
  fv4 a = ((const fv4*)(wte + (size_t)tk * E_))[threadIdx.x];
  fv4 p = ((const fv4*)(wpe + (size_t)t * E_))[threadIdx.x];
  ((fv4*)(x + (size_t)row * E_))[threadIdx.x] = a + p;
}

// ---------------- layernorm (f32 in, bf16 out), one block per row ----------------
__global__ __launch_bounds__(256) void k_ln(const float* __restrict__ x,
                                            const float* __restrict__ g,
                                            const float* __restrict__ b,
                                            short* __restrict__ y) {
  int row = blockIdx.x;
  int tid = threadIdx.x;
  fv4 v = ((const fv4*)(x + (size_t)row * E_))[tid];
  float s = v[0] + v[1] + v[2] + v[3];
  float q = v[0]*v[0] + v[1]*v[1] + v[2]*v[2] + v[3]*v[3];
  for (int off = 32; off; off >>= 1) {
    s += __shfl_down(s, off);
    q += __shfl_down(q, off);
  }
  __shared__ float ss[4], qs[4];
  int lane = tid & 63, w = tid >> 6;
  if (lane == 0) { ss[w] = s; qs[w] = q; }
  __syncthreads();
  s = ss[0] + ss[1] + ss[2] + ss[3];
  q = qs[0] + qs[1] + qs[2] + qs[3];
  float mu = s * (1.0f / E_);
  float var = q * (1.0f / E_) - mu * mu;
  float rs = rsqrtf(var + 1e-5f);
  int c = tid << 2;
  sv4 o;
  for (int i = 0; i < 4; ++i) o[i] = f2bf((v[i] - mu) * rs * g[c + i] + b[c + i]);
  ((sv4*)(y + (size_t)row * E_))[tid] = o;
}

// ------------- convert+transpose: f32 [K][N] -> bf16 [N][K] (32x32 tiles) -------------
__global__ __launch_bounds__(256) void k_convT(const float* __restrict__ src,
                                               short* __restrict__ dst, int K, int N) {
  __shared__ float tile[32][33];
  int n0 = blockIdx.x << 5, k0 = blockIdx.y << 5;
  int tx = threadIdx.x & 31, ty = threadIdx.x >> 5;
  for (int r = 0; r < 4; ++r) {
    int k = (r << 3) + ty;
    tile[k][tx] = src[(size_t)(k0 + k) * N + n0 + tx];
  }
  __syncthreads();
  for (int r = 0; r < 4; ++r) {
    int n = (r << 3) + ty;
    dst[(size_t)(n0 + n) * K + k0 + tx] = f2bf(tile[tx][n]);
  }
}

// ---------------- GEMM: C[M,N] = A[M,K](bf16) * Bt[N,K](bf16)^T, epilogues ----------------
// EPI 0: bf16 out.  1: f32 resid += acc+bias.  2: bf16 out = relu(acc+bias).  3: f32 out = acc+bias.
template <int EPI>
__global__ __launch_bounds__(256) void k_gemm(const short* __restrict__ A,
                                              const short* __restrict__ Bt,
                                              const float* __restrict__ bias,
                                              void* __restrict__ outp,
                                              int M, int N, int K) {
  __shared__ short As[128 * 32];
  __shared__ short Bs[128 * 32];
  int tid = threadIdx.x, lane = tid & 63, w = tid >> 6;
  int m0 = blockIdx.y << 7, n0 = blockIdx.x << 7;
  int wr = (w >> 1) << 6, wc = (w & 1) << 6;
  fv4 acc[4][4] = {};
  int srow = (w << 4) + (lane >> 2);
  int scol = (lane & 3) << 3;
  const short* ag = A  + (size_t)(m0 + srow) * K + scol;
  const short* bg = Bt + (size_t)(n0 + srow) * K + scol;
  short* asd = &As[w << 9];
  short* bsd = &Bs[w << 9];
  for (int kt = 0; kt < K; kt += 32) {
    __syncthreads();
    gload16(ag + kt, asd);
    gload16(ag + kt + (size_t)64 * K, asd + 2048);
    gload16(bg + kt, bsd);
    gload16(bg + kt + (size_t)64 * K, bsd + 2048);
    __syncthreads();
    bh8 af[4], bf[4];
    int rb = wr + (lane & 15);
    int cb = wc + (lane & 15);
    int kb = (lane >> 4) << 3;
    for (int i = 0; i < 4; ++i) af[i] = *(const bh8*)&As[(rb + (i << 4)) * 32 + kb];
    for (int i = 0; i < 4; ++i) bf[i] = *(const bh8*)&Bs[(cb + (i << 4)) * 32 + kb];
    for (int i = 0; i < 4; ++i)
      for (int j = 0; j < 4; ++j)
        acc[i][j] = MFMA(af[i], bf[j], acc[i][j]);
  }
  int col0 = n0 + wc + (lane & 15);
  int row0 = m0 + wr + ((lane >> 4) << 2);
  for (int j = 0; j < 4; ++j) {
    int col = col0 + (j << 4);
    float bv = 0.f;
    if constexpr (EPI != 0) bv = bias[col];
    for (int i = 0; i < 4; ++i) {
      for (int e = 0; e < 4; ++e) {
        int row = row0 + (i << 4) + e;
        float v = acc[i][j][e] + bv;
        size_t idx = (size_t)row * N + col;
        if constexpr (EPI == 0)      ((short*)outp)[idx] = f2bf(v);
        else if constexpr (EPI == 1) ((float*)outp)[idx] += v;
        else if constexpr (EPI == 2) ((short*)outp)[idx] = f2bf(fmaxf(v, 0.f));
        else                         ((float*)outp)[idx] = v;
      }
    }
  }
}

// ---------------- flash attention, causal. qkv bf16 [4096][3072], out bf16 [4096][1024] --------
// Swapped form: S^T = mfma(A=K, B=Q) so each lane's softmax state is for q = lane&15.
__global__ __launch_bounds__(256) void k_attn(const short* __restrict__ qkv,
                                              short* __restrict__ o) {
  int qt = blockIdx.x, h = blockIdx.y, b = blockIdx.z;
  __shared__ short Ks[32 * 64];   // [key][dh]
  __shared__ short Vt[64 * 32];   // [dh][key]
  int tid = threadIdx.x, lane = tid & 63, w = tid >> 6;
  int qrow = (qt << 6) + (w << 4) + (lane & 15);
  size_t rowbase = (size_t)b * T_;
  const short* qp = qkv + (rowbase + qrow) * 3072 + h * 64;
  bh8 qf0 = *(const bh8*)(qp + ((lane >> 4) << 3));
  bh8 qf1 = *(const bh8*)(qp + 32 + ((lane >> 4) << 3));
  float m_run = -1e30f, lsum = 0.f;
  fv4 oa[4] = {};
  int nt = 2 * qt + 2;
  for (int kt = 0; kt < nt; ++kt) {
    __syncthreads();
    {
      int krow = (kt << 5) + (w << 3) + (lane >> 3);
      const short* kg = qkv + (rowbase + krow) * 3072 + 1024 + h * 64 + ((lane & 7) << 3);
      gload16(kg, &Ks[w << 9]);
    }
    if (tid < 128) {   // V^T staging: pack adjacent-key pairs into b32 writes
      int key2 = (tid & 15) << 1;
      int dhc = tid >> 4;
      const short* vg = qkv + (rowbase + (kt << 5) + key2) * 3072 + 2048 + h * 64 + (dhc << 3);
      uv4 v0 = *(const uv4*)vg;
      uv4 v1 = *(const uv4*)(vg + 3072);
      for (int d2 = 0; d2 < 4; ++d2) {
        unsigned w0 = v0[d2], w1 = v1[d2];
        int dh = (dhc << 3) + (d2 << 1);
        *(unsigned*)&Vt[dh * 32 + key2]       = (w0 & 0xFFFFu) | (w1 << 16);
        *(unsigned*)&Vt[(dh + 1) * 32 + key2] = (w0 >> 16) | (w1 & 0xFFFF0000u);
      }
    }
    __syncthreads();
    fv4 st[2];
    for (int f = 0; f < 2; ++f) {
      const short* kb = &Ks[((f << 4) + (lane & 15)) * 64 + ((lane >> 4) << 3)];
      bh8 k0 = *(const bh8*)kb;
      bh8 k1 = *(const bh8*)(kb + 32);
      fv4 z = {};
      z = MFMA(k0, qf0, z);
      z = MFMA(k1, qf1, z);
      st[f] = z;
    }
    float p[8];
    float pmax = -1e30f;
    int keybase = (kt << 5) + ((lane >> 4) << 2);
    for (int f = 0; f < 2; ++f)
      for (int i = 0; i < 4; ++i) {
        int key = keybase + (f << 4) + i;
        float sc = st[f][i] * 0.125f;
        sc = (key <= qrow) ? sc : -1e30f;
        p[(f << 2) + i] = sc;
        pmax = fmaxf(pmax, sc);
      }
    pmax = fmaxf(pmax, __shfl_xor(pmax, 16));
    pmax = fmaxf(pmax, __shfl_xor(pmax, 32));
    float m_new = fmaxf(m_run, pmax);
    float alpha = exp2f((m_run - m_new) * 1.44269504f);
    float psum = 0.f;
    for (int i = 0; i < 8; ++i) {
      float e = exp2f((p[i] - m_new) * 1.44269504f);
      p[i] = e;
      psum += e;
    }
    psum += __shfl_xor(psum, 16);
    psum += __shfl_xor(psum, 32);
    lsum = lsum * alpha + psum;
    m_run = m_new;
    bh8 pf;   // P^T as B-operand: j<4 -> key 4g+j (frag0), j>=4 -> key 16+4g+(j-4) (frag1)
    for (int i = 0; i < 4; ++i) { pf[i] = f2bf(p[i]); pf[i + 4] = f2bf(p[4 + i]); }
    for (int db = 0; db < 4; ++db) {
      const short* vb = &Vt[((db << 4) + (lane & 15)) * 32 + ((lane >> 4) << 2)];
      uv2 a0 = *(const uv2*)vb;
      uv2 a1 = *(const uv2*)(vb + 16);
      bh8 vf;
      ((uv2*)&vf)[0] = a0;
      ((uv2*)&vf)[1] = a1;
      fv4 t = oa[db];
      for (int e = 0; e < 4; ++e) t[e] *= alpha;
      oa[db] = MFMA(vf, pf, t);
    }
  }
  float inv = 1.0f / lsum;
  short* ob = o + (rowbase + qrow) * E_ + h * 64;
  for (int db = 0; db < 4; ++db)
    for (int e = 0; e < 4; ++e)
      ob[(db << 4) + ((lane >> 4) << 2) + e] = f2bf(oa[db][e] * inv);
}

extern "C" void kernel_launch(void* const* d_in, const int* in_sizes, int n_in,
                              void* d_out, int out_size, void* d_ws, size_t ws_size,
                              hipStream_t stream) {
  const int*   tok    = (const int*)d_in[0];
  const float* wte    = (const float*)d_in[1];
  const float* wpe    = (const float*)d_in[2];
  const float* qkv_w  = (const float*)d_in[3];
  const float* proj_w = (const float*)d_in[4];
  const float* proj_b = (const float*)d_in[5];
  const float* ff1_w  = (const float*)d_in[6];
  const float* ff1_b  = (const float*)d_in[7];
  const float* ff2_w  = (const float*)d_in[8];
  const float* ff2_b  = (const float*)d_in[9];
  const float* ln1_g  = (const float*)d_in[10];
  const float* ln1_b  = (const float*)d_in[11];
  const float* ln2_g  = (const float*)d_in[12];
  const float* ln2_b  = (const float*)d_in[13];
  const float* lnf_g  = (const float*)d_in[14];
  const float* lnf_b  = (const float*)d_in[15];
  const float* head_w = (const float*)d_in[16];
  const float* head_b = (const float*)d_in[17];

  char* ws = (char*)d_ws;
  float* x     = (float*)ws;  ws += (size_t)ROWS_ * E_ * 4;       // f32 residual
  short* xbf   = (short*)ws;  ws += (size_t)ROWS_ * E_ * 2;       // LN output bf16
  short* qkvb  = (short*)ws;  ws += (size_t)ROWS_ * 3072 * 2;     // qkv bf16
  short* attno = (short*)ws;  ws += (size_t)ROWS_ * E_ * 2;       // attn out bf16
  short* ffh   = (short*)ws;  ws += (size_t)ROWS_ * 4096 * 2;     // ff hidden bf16
  short* wbuf  = (short*)ws;  ws += (size_t)32000 * 1024 * 2;     // transposed bf16 weights

  k_embed<<<ROWS_, 256, 0, stream>>>(tok, wte, wpe, x);
  for (int l = 0; l < L_; ++l) {
    k_ln<<<ROWS_, 256, 0, stream>>>(x, ln1_g + l * E_, ln1_b + l * E_, xbf);
    k_convT<<<dim3(96, 32), 256, 0, stream>>>(qkv_w + (size_t)l * E_ * 3072, wbuf, E_, 3072);
    k_gemm<0><<<dim3(24, 32), 256, 0, stream>>>(xbf, wbuf, nullptr, qkvb, ROWS_, 3072, E_);
    k_attn<<<dim3(16, H_, 4), 256, 0, stream>>>(qkvb, attno);
    k_convT<<<dim3(32, 32), 256, 0, stream>>>(proj_w + (size_t)l * E_ * E_, wbuf, E_, E_);
    k_gemm<1><<<dim3(8, 32), 256, 0, stream>>>(attno, wbuf, proj_b + l * E_, x, ROWS_, E_, E_);
    k_ln<<<ROWS_, 256, 0, stream>>>(x, ln2_g + l * E_, ln2_b + l * E_, xbf);
    k_convT<<<dim3(128, 32), 256, 0, stream>>>(ff1_w + (size_t)l * E_ * 4096, wbuf, E_, 4096);
    k_gemm<2><<<dim3(32, 32), 256, 0, stream>>>(xbf, wbuf, ff1_b + l * 4096, ffh, ROWS_, 4096, E_);
    k_convT<<<dim3(32, 128), 256, 0, stream>>>(ff2_w + (size_t)l * 4096 * E_, wbuf, 4096, E_);
    k_gemm<1><<<dim3(8, 32), 256, 0, stream>>>(ffh, wbuf, ff2_b + l * E_, x, ROWS_, E_, 4096);
  }
  k_ln<<<ROWS_, 256, 0, stream>>>(x, lnf_g, lnf_b, xbf);
  k_convT<<<dim3(1000, 32), 256, 0, stream>>>(head_w, wbuf, E_, 32000);
  k_gemm<3><<<dim3(250, 32), 256, 0, stream>>>(xbf, wbuf, head_b, d_out, ROWS_, 32000, E_);
}

// Round 6
// 3981.038 us; speedup vs baseline: 1.0094x; 1.0094x over previous
//
#include <hip/hip_runtime.h>
#include <stdint.h>

#define T_ 1024
#define E_ 1024
#define L_ 8
#define H_ 16
#define ROWS_ 4096   // B*T

typedef __attribute__((ext_vector_type(8))) short bh8;   // 8 x bf16 (MFMA A/B frag)
typedef __attribute__((ext_vector_type(4))) short sv4;
typedef __attribute__((ext_vector_type(4))) float fv4;
typedef __attribute__((ext_vector_type(4))) unsigned int uv4;
typedef __attribute__((ext_vector_type(2))) unsigned int uv2;

#define MFMA(a, b, c) __builtin_amdgcn_mfma_f32_16x16x32_bf16(a, b, c, 0, 0, 0)

__device__ __forceinline__ short f2bf(float f) {
  union { float f; unsigned u; } a; a.f = f;
  unsigned r = a.u + 0x7FFFu + ((a.u >> 16) & 1u);   // RNE
  return (short)(r >> 16);
}

// global -> LDS direct copy, 16B per lane. LDS dest must be wave-uniform base.
__device__ __forceinline__ void gload16(const void* g, void* l) {
  auto gp = reinterpret_cast<__attribute__((address_space(1))) char*>(
      reinterpret_cast<uintptr_t>(g));
  auto lp = reinterpret_cast<__attribute__((address_space(3))) char*>(
      reinterpret_cast<uintptr_t>(l));
  __builtin_amdgcn_global_load_lds(gp, lp, 16, 0, 0);
}

// ---------------- embedding: x[row] = wte[tok[row]] + wpe[row%T] ----------------
__global__ __launch_bounds__(256) void k_embed(const int* __restrict__ tok,
                                               const float* __restrict__ wte,
                                               const float* __restrict__ wpe,
                                               float* __restrict__ x) {
  int row = blockIdx.x;
  int t = row & (T_ - 1);
  int tk = tok[row];
  fv4 a = ((const fv4*)(wte + (size_t)tk * E_))[threadIdx.x];
  fv4 p = ((const fv4*)(wpe + (size_t)t * E_))[threadIdx.x];
  ((fv4*)(x + (size_t)row * E_))[threadIdx.x] = a + p;
}

// ---------------- layernorm (f32 in, bf16 out), one block per row ----------------
__global__ __launch_bounds__(256) void k_ln(const float* __restrict__ x,
                                            const float* __restrict__ g,
                                            const float* __restrict__ b,
                                            short* __restrict__ y) {
  int row = blockIdx.x;
  int tid = threadIdx.x;
  fv4 v = ((const fv4*)(x + (size_t)row * E_))[tid];
  float s = v[0] + v[1] + v[2] + v[3];
  float q = v[0]*v[0] + v[1]*v[1] + v[2]*v[2] + v[3]*v[3];
  for (int off = 32; off; off >>= 1) {
    s += __shfl_down(s, off);
    q += __shfl_down(q, off);
  }
  __shared__ float ss[4], qs[4];
  int lane = tid & 63, w = tid >> 6;
  if (lane == 0) { ss[w] = s; qs[w] = q; }
  __syncthreads();
  s = ss[0] + ss[1] + ss[2] + ss[3];
  q = qs[0] + qs[1] + qs[2] + qs[3];
  float mu = s * (1.0f / E_);
  float var = q * (1.0f / E_) - mu * mu;
  float rs = rsqrtf(var + 1e-5f);
  int c = tid << 2;
  sv4 o;
  for (int i = 0; i < 4; ++i) o[i] = f2bf((v[i] - mu) * rs * g[c + i] + b[c + i]);
  ((sv4*)(y + (size_t)row * E_))[tid] = o;
}

// ------------- convert+transpose: f32 [K][N] -> bf16 [N][K] (32x32 tiles) -------------
__global__ __launch_bounds__(256) void k_convT(const float* __restrict__ src,
                                               short* __restrict__ dst, int K, int N) {
  __shared__ float tile[32][33];
  int n0 = blockIdx.x << 5, k0 = blockIdx.y << 5;
  int tx = threadIdx.x & 31, ty = threadIdx.x >> 5;
  for (int r = 0; r < 4; ++r) {
    int k = (r << 3) + ty;
    tile[k][tx] = src[(size_t)(k0 + k) * N + n0 + tx];
  }
  __syncthreads();
  for (int r = 0; r < 4; ++r) {
    int n = (r << 3) + ty;
    dst[(size_t)(n0 + n) * K + k0 + tx] = f2bf(tile[tx][n]);
  }
}

// ---------------- GEMM: C[M,N] = A[M,K](bf16) * Bt[N,K](bf16)^T, epilogues ----------------
// LDS tiles are XOR-swizzled: within each 64B row, 16B chunk slot s holds global
// chunk s ^ ((row>>1)&3). Staging pre-swizzles the GLOBAL source (global_load_lds
// writes linearly); reads apply the same XOR. 8-way bank conflict -> 2-way (free).
// EPI 0: bf16 out.  1: f32 resid += acc+bias.  2: bf16 out = relu(acc+bias).  3: f32 out = acc+bias.
// SWAP: m-tiles on blockIdx.x (consecutive blocks share the B-panel) — for the
// 250-n-tile head GEMM where B no longer fits L2 and gets re-fetched per m-row.
template <int EPI, bool SWAP = false>
__global__ __launch_bounds__(256) void k_gemm(const short* __restrict__ A,
                                              const short* __restrict__ Bt,
                                              const float* __restrict__ bias,
                                              void* __restrict__ outp,
                                              int M, int N, int K) {
  __shared__ short As[128 * 32];
  __shared__ short Bs[128 * 32];
  int tid = threadIdx.x, lane = tid & 63, w = tid >> 6;
  int m0, n0;
  if constexpr (SWAP) { m0 = blockIdx.x << 7; n0 = blockIdx.y << 7; }
  else                { m0 = blockIdx.y << 7; n0 = blockIdx.x << 7; }
  int wr = (w >> 1) << 6, wc = (w & 1) << 6;
  fv4 acc[4][4] = {};
  int srow = (w << 4) + (lane >> 2);
  int scol = ((lane & 3) ^ ((lane >> 3) & 3)) << 3;   // pre-swizzled global k-chunk
  const short* ag = A  + (size_t)(m0 + srow) * K + scol;
  const short* bg = Bt + (size_t)(n0 + srow) * K + scol;
  short* asd = &As[w << 9];
  short* bsd = &Bs[w << 9];
  for (int kt = 0; kt < K; kt += 32) {
    __syncthreads();
    gload16(ag + kt, asd);
    gload16(ag + kt + (size_t)64 * K, asd + 2048);
    gload16(bg + kt, bsd);
    gload16(bg + kt + (size_t)64 * K, bsd + 2048);
    __syncthreads();
    bh8 af[4], bf[4];
    int rb = wr + (lane & 15);
    int cb = wc + (lane & 15);
    int kb = ((lane >> 4) ^ ((lane >> 1) & 3)) << 3;  // swizzled read slot
    for (int i = 0; i < 4; ++i) af[i] = *(const bh8*)&As[(rb + (i << 4)) * 32 + kb];
    for (int i = 0; i < 4; ++i) bf[i] = *(const bh8*)&Bs[(cb + (i << 4)) * 32 + kb];
    for (int i = 0; i < 4; ++i)
      for (int j = 0; j < 4; ++j)
        acc[i][j] = MFMA(af[i], bf[j], acc[i][j]);
  }
  int col0 = n0 + wc + (lane & 15);
  int row0 = m0 + wr + ((lane >> 4) << 2);
  for (int j = 0; j < 4; ++j) {
    int col = col0 + (j << 4);
    float bv = 0.f;
    if constexpr (EPI != 0) bv = bias[col];
    for (int i = 0; i < 4; ++i) {
      for (int e = 0; e < 4; ++e) {
        int row = row0 + (i << 4) + e;
        float v = acc[i][j][e] + bv;
        size_t idx = (size_t)row * N + col;
        if constexpr (EPI == 0)      ((short*)outp)[idx] = f2bf(v);
        else if constexpr (EPI == 1) ((float*)outp)[idx] += v;
        else if constexpr (EPI == 2) ((short*)outp)[idx] = f2bf(fmaxf(v, 0.f));
        else                         ((float*)outp)[idx] = v;
      }
    }
  }
}

// ---------------- flash attention, causal. qkv bf16 [4096][3072], out bf16 [4096][1024] --------
// Swapped form: S^T = mfma(A=K, B=Q) so each lane's softmax state is for q = lane&15.
__global__ __launch_bounds__(256) void k_attn(const short* __restrict__ qkv,
                                              short* __restrict__ o) {
  int qt = blockIdx.x, h = blockIdx.y, b = blockIdx.z;
  __shared__ short Ks[32 * 64];   // [key][dh]
  __shared__ short Vt[64 * 32];   // [dh][key]
  int tid = threadIdx.x, lane = tid & 63, w = tid >> 6;
  int qrow = (qt << 6) + (w << 4) + (lane & 15);
  size_t rowbase = (size_t)b * T_;
  const short* qp = qkv + (rowbase + qrow) * 3072 + h * 64;
  bh8 qf0 = *(const bh8*)(qp + ((lane >> 4) << 3));
  bh8 qf1 = *(const bh8*)(qp + 32 + ((lane >> 4) << 3));
  float m_run = -1e30f, lsum = 0.f;
  fv4 oa[4] = {};
  int nt = 2 * qt + 2;
  for (int kt = 0; kt < nt; ++kt) {
    __syncthreads();
    {
      int krow = (kt << 5) + (w << 3) + (lane >> 3);
      const short* kg = qkv + (rowbase + krow) * 3072 + 1024 + h * 64 + ((lane & 7) << 3);
      gload16(kg, &Ks[w << 9]);
    }
    if (tid < 128) {   // V^T staging: pack adjacent-key pairs into b32 writes
      int key2 = (tid & 15) << 1;
      int dhc = tid >> 4;
      const short* vg = qkv + (rowbase + (kt << 5) + key2) * 3072 + 2048 + h * 64 + (dhc << 3);
      uv4 v0 = *(const uv4*)vg;
      uv4 v1 = *(const uv4*)(vg + 3072);
      for (int d2 = 0; d2 < 4; ++d2) {
        unsigned w0 = v0[d2], w1 = v1[d2];
        int dh = (dhc << 3) + (d2 << 1);
        *(unsigned*)&Vt[dh * 32 + key2]       = (w0 & 0xFFFFu) | (w1 << 16);
        *(unsigned*)&Vt[(dh + 1) * 32 + key2] = (w0 >> 16) | (w1 & 0xFFFF0000u);
      }
    }
    __syncthreads();
    fv4 st[2];
    for (int f = 0; f < 2; ++f) {
      const short* kb = &Ks[((f << 4) + (lane & 15)) * 64 + ((lane >> 4) << 3)];
      bh8 k0 = *(const bh8*)kb;
      bh8 k1 = *(const bh8*)(kb + 32);
      fv4 z = {};
      z = MFMA(k0, qf0, z);
      z = MFMA(k1, qf1, z);
      st[f] = z;
    }
    float p[8];
    float pmax = -1e30f;
    int keybase = (kt << 5) + ((lane >> 4) << 2);
    for (int f = 0; f < 2; ++f)
      for (int i = 0; i < 4; ++i) {
        int key = keybase + (f << 4) + i;
        float sc = st[f][i] * 0.125f;
        sc = (key <= qrow) ? sc : -1e30f;
        p[(f << 2) + i] = sc;
        pmax = fmaxf(pmax, sc);
      }
    pmax = fmaxf(pmax, __shfl_xor(pmax, 16));
    pmax = fmaxf(pmax, __shfl_xor(pmax, 32));
    float m_new = fmaxf(m_run, pmax);
    float alpha = exp2f((m_run - m_new) * 1.44269504f);
    float psum = 0.f;
    for (int i = 0; i < 8; ++i) {
      float e = exp2f((p[i] - m_new) * 1.44269504f);
      p[i] = e;
      psum += e;
    }
    psum += __shfl_xor(psum, 16);
    psum += __shfl_xor(psum, 32);
    lsum = lsum * alpha + psum;
    m_run = m_new;
    bh8 pf;   // P^T as B-operand: j<4 -> key 4g+j (frag0), j>=4 -> key 16+4g+(j-4) (frag1)
    for (int i = 0; i < 4; ++i) { pf[i] = f2bf(p[i]); pf[i + 4] = f2bf(p[4 + i]); }
    for (int db = 0; db < 4; ++db) {
      const short* vb = &Vt[((db << 4) + (lane & 15)) * 32 + ((lane >> 4) << 2)];
      uv2 a0 = *(const uv2*)vb;
      uv2 a1 = *(const uv2*)(vb + 16);
      bh8 vf;
      ((uv2*)&vf)[0] = a0;
      ((uv2*)&vf)[1] = a1;
      fv4 t = oa[db];
      for (int e = 0; e < 4; ++e) t[e] *= alpha;
      oa[db] = MFMA(vf, pf, t);
    }
  }
  float inv = 1.0f / lsum;
  short* ob = o + (rowbase + qrow) * E_ + h * 64;
  for (int db = 0; db < 4; ++db)
    for (int e = 0; e < 4; ++e)
      ob[(db << 4) + ((lane >> 4) << 2) + e] = f2bf(oa[db][e] * inv);
}

extern "C" void kernel_launch(void* const* d_in, const int* in_sizes, int n_in,
                              void* d_out, int out_size, void* d_ws, size_t ws_size,
                              hipStream_t stream) {
  const int*   tok    = (const int*)d_in[0];
  const float* wte    = (const float*)d_in[1];
  const float* wpe    = (const float*)d_in[2];
  const float* qkv_w  = (const float*)d_in[3];
  const float* proj_w = (const float*)d_in[4];
  const float* proj_b = (const float*)d_in[5];
  const float* ff1_w  = (const float*)d_in[6];
  const float* ff1_b  = (const float*)d_in[7];
  const float* ff2_w  = (const float*)d_in[8];
  const float* ff2_b  = (const float*)d_in[9];
  const float* ln1_g  = (const float*)d_in[10];
  const float* ln1_b  = (const float*)d_in[11];
  const float* ln2_g  = (const float*)d_in[12];
  const float* ln2_b  = (const float*)d_in[13];
  const float* lnf_g  = (const float*)d_in[14];
  const float* lnf_b  = (const float*)d_in[15];
  const float* head_w = (const float*)d_in[16];
  const float* head_b = (const float*)d_in[17];

  char* ws = (char*)d_ws;
  float* x     = (float*)ws;  ws += (size_t)ROWS_ * E_ * 4;       // f32 residual
  short* xbf   = (short*)ws;  ws += (size_t)ROWS_ * E_ * 2;       // LN output bf16
  short* qkvb  = (short*)ws;  ws += (size_t)ROWS_ * 3072 * 2;     // qkv bf16
  short* attno = (short*)ws;  ws += (size_t)ROWS_ * E_ * 2;       // attn out bf16
  short* ffh   = (short*)ws;  ws += (size_t)ROWS_ * 4096 * 2;     // ff hidden bf16
  short* wbuf  = (short*)ws;  ws += (size_t)32000 * 1024 * 2;     // transposed bf16 weights

  k_embed<<<ROWS_, 256, 0, stream>>>(tok, wte, wpe, x);
  for (int l = 0; l < L_; ++l) {
    k_ln<<<ROWS_, 256, 0, stream>>>(x, ln1_g + l * E_, ln1_b + l * E_, xbf);
    k_convT<<<dim3(96, 32), 256, 0, stream>>>(qkv_w + (size_t)l * E_ * 3072, wbuf, E_, 3072);
    k_gemm<0><<<dim3(24, 32), 256, 0, stream>>>(xbf, wbuf, nullptr, qkvb, ROWS_, 3072, E_);
    k_attn<<<dim3(16, H_, 4), 256, 0, stream>>>(qkvb, attno);
    k_convT<<<dim3(32, 32), 256, 0, stream>>>(proj_w + (size_t)l * E_ * E_, wbuf, E_, E_);
    k_gemm<1><<<dim3(8, 32), 256, 0, stream>>>(attno, wbuf, proj_b + l * E_, x, ROWS_, E_, E_);
    k_ln<<<ROWS_, 256, 0, stream>>>(x, ln2_g + l * E_, ln2_b + l * E_, xbf);
    k_convT<<<dim3(128, 32), 256, 0, stream>>>(ff1_w + (size_t)l * E_ * 4096, wbuf, E_, 4096);
    k_gemm<2><<<dim3(32, 32), 256, 0, stream>>>(xbf, wbuf, ff1_b + l * 4096, ffh, ROWS_, 4096, E_);
    k_convT<<<dim3(32, 128), 256, 0, stream>>>(ff2_w + (size_t)l * 4096 * E_, wbuf, 4096, E_);
    k_gemm<1><<<dim3(8, 32), 256, 0, stream>>>(ffh, wbuf, ff2_b + l * E_, x, ROWS_, E_, 4096);
  }
  k_ln<<<ROWS_, 256, 0, stream>>>(x, lnf_g, lnf_b, xbf);
  k_convT<<<dim3(1000, 32), 256, 0, stream>>>(head_w, wbuf, E_, 32000);
  k_gemm<3, true><<<dim3(32, 250), 256, 0, stream>>>(xbf, wbuf, head_b, d_out, ROWS_, 32000, E_);
}